// Round 15
// baseline (241.210 us; speedup 1.0000x reference)
//
#include <hip/hip_runtime.h>
#include <hip/hip_bf16.h>

// ComplexAttention: x(2,2048,1024) fp32, 8x W(1024,1024)+b(1024).
// Pipeline: cvt -> 6 proj GEMMs (V written pre-transposed) -> flash attn -> 2 final GEMMs.
// R1-R8: ladder to 175.6us. R9/R10 FAILED. R11: 32x32 attn, 175.0us (best).
// R12 dbuf FLAT; R13 occupancy FLAT -> attn is LDS-PIPE-bound (~1.1 ds_read_b128 per
//      MFMA; LDS 1 port/CU vs MFMA 4 -> MfmaUtil capped ~18%). Lever = reads per MFMA.
// R14: dual q-fragment sets per wave (64 q-rows in regs): every kf/vf read feeds 2 MFMAs;
//      4 waves take disjoint 32-k windows of a shared 128-k tile (each byte ds_read once);
//      4-way k-split merged through freed LDS in 2 dv-rounds. reads/MFMA ~0.6 (2x better).

typedef __attribute__((ext_vector_type(8))) __bf16 bf16x8;
typedef __attribute__((ext_vector_type(4))) float f32x4;
typedef __attribute__((ext_vector_type(16))) float f32x16;
typedef unsigned short u16;
typedef unsigned int u32;

#define L2E 1.44269504088896340736f
#define NEG16L2E (-23.0831207542234f)   // -16 * log2(e)

__device__ __forceinline__ void gl2lds16(const void* g, void* l) {
  __builtin_amdgcn_global_load_lds(
      (const __attribute__((address_space(1))) unsigned int*)g,
      (__attribute__((address_space(3))) unsigned int*)l, 16, 0, 0);
}

__device__ __forceinline__ u16 f2bf(float f) {
  union { float f; unsigned u; } v;
  v.f = f;
  unsigned r = v.u + 0x7FFFu + ((v.u >> 16) & 1u);
  return (u16)(r >> 16);
}

__device__ __forceinline__ u32 cvtpk(float lo, float hi) {
  u32 d;
  asm("v_cvt_pk_bf16_f32 %0, %1, %2" : "=v"(d) : "v"(lo), "v"(hi));
  return d;
}

// ---------------- fp32 -> bf16 convert (both tensors, one launch) ----------------
__global__ void cvt_bf16_2(const float* __restrict__ a, const float* __restrict__ bsrc,
                           u16* __restrict__ oa, u16* __restrict__ ob, int n) {
  const float* in = blockIdx.y ? bsrc : a;
  u16* out = blockIdx.y ? ob : oa;
  int stride = gridDim.x * blockDim.x * 4;
  for (int i = (blockIdx.x * blockDim.x + threadIdx.x) * 4; i < n; i += stride) {
    float4 v = *(const float4*)(in + i);
    ushort4 o;
    o.x = f2bf(v.x); o.y = f2bf(v.y); o.z = f2bf(v.z); o.w = f2bf(v.w);
    *(ushort4*)(out + i) = o;
  }
}

// ---------------- W (K x N) fp32 -> Wt (N x K) bf16 ----------------
struct WPtrs { const float* w[8]; };

__global__ void cvt_w_t(WPtrs ptrs, u16* __restrict__ out) {
  __shared__ float tile[32][33];
  const float* W = ptrs.w[blockIdx.z];
  u16* o = out + ((size_t)blockIdx.z << 20);
  int tx = threadIdx.x & 31, ty = threadIdx.x >> 5;
  int bx = blockIdx.x * 32, by = blockIdx.y * 32;
#pragma unroll
  for (int k = 0; k < 4; k++) {
    int r = by + ty + k * 8;
    tile[ty + k * 8][tx] = W[(size_t)r * 1024 + bx + tx];
  }
  __syncthreads();
#pragma unroll
  for (int k = 0; k < 4; k++) {
    int n = bx + ty + k * 8;
    o[(size_t)n * 1024 + by + tx] = f2bf(tile[tx][ty + k * 8]);
  }
}

// ---------------- batched 128x128 GEMM, A(M x 1024) * Wt(N x 1024)^T + bias ----------------
struct GemmArgs {
  const u16* A[6];
  const u16* Wt[6];
  const float* bias[6];
  void* dst[6];
  int off[6];
  int vt[6];
  float scale[6];
};

template <int MODE>
__global__ __launch_bounds__(256, 2) void gemm_bf16(GemmArgs args) {
  extern __shared__ u16 dynpad[];   // 16KB pad at launch -> 48KB/block -> 3 blocks/CU
  const int z = blockIdx.z;
  const u16* __restrict__ A = args.A[z];
  const u16* __restrict__ Bt = args.Wt[z];
  const float* __restrict__ bias = args.bias[z];
  const int brow = blockIdx.x * 128;
  const int bcol = blockIdx.y * 128;

  __shared__ u16 smem[2][2][128 * 32];

  const int tid = threadIdx.x;
  const int w = tid >> 6, lane = tid & 63;
  const int ql = lane & 15, hi = lane >> 4;
  const int wrow = (w >> 1) * 64, wcol = (w & 1) * 64;

  if (args.off[z] == -12345) ((volatile u16*)dynpad)[0] = 0;  // keep dyn-LDS alive, never true

  f32x4 acc[4][4] = {};

  auto stage = [&](int buf, int t) {
    int k0 = t * 32;
#pragma unroll
    for (int s = 0; s < 2; s++) {
      int q = w * 2 + s;
      int lr = q * 16 + (lane >> 2);
      int csrc = (lane & 3) ^ ((lr >> 1) & 3);
      gl2lds16(A + (size_t)(brow + lr) * 1024 + k0 + csrc * 8, &smem[0][buf][q * 512]);
    }
#pragma unroll
    for (int s = 0; s < 2; s++) {
      int q = w * 2 + s;
      int lr = q * 16 + (lane >> 2);
      int csrc = (lane & 3) ^ ((lr >> 1) & 3);
      gl2lds16(Bt + (size_t)(bcol + lr) * 1024 + k0 + csrc * 8, &smem[1][buf][q * 512]);
    }
  };

  stage(0, 0);
  __syncthreads();

  int buf = 0;
  for (int t = 0; t < 32; t++) {
    if (t + 1 < 32) stage(buf ^ 1, t + 1);
    bf16x8 a[4], b[4];
#pragma unroll
    for (int i = 0; i < 4; i++) {
      int row = wrow + i * 16 + ql;
      int cs = hi ^ ((row >> 1) & 3);
      a[i] = *(const bf16x8*)&smem[0][buf][row * 32 + cs * 8];
      int col = wcol + i * 16 + ql;
      int cs2 = hi ^ ((col >> 1) & 3);
      b[i] = *(const bf16x8*)&smem[1][buf][col * 32 + cs2 * 8];
    }
#pragma unroll
    for (int i = 0; i < 4; i++)
#pragma unroll
      for (int j = 0; j < 4; j++)
        acc[i][j] = __builtin_amdgcn_mfma_f32_16x16x32_bf16(a[i], b[j], acc[i][j], 0, 0, 0);
    __syncthreads();
    buf ^= 1;
  }

  const int off = args.off[z];
  const float scl = args.scale[z];

  if (MODE == 1 && args.vt[z]) {
    // ---- V path: transpose C-tile in LDS, write Vt[(bh,dv,t)] coalesced ----
    u16* sm = &smem[0][0][0];
    const int bb = brow >> 11, t0 = brow & 2047;
    const int h0 = bcol >> 6;
    u16* dstV = (u16*)args.dst[z];
#pragma unroll
    for (int p = 0; p < 2; p++) {
      if ((w & 1) == p) {
#pragma unroll
        for (int i = 0; i < 4; i++)
#pragma unroll
          for (int j = 0; j < 4; j++) {
            int col_local = j * 16 + ql;
            int row_base = wrow + i * 16 + hi * 4;
            float bv = bias[bcol + p * 64 + col_local];
            union { __bf16 hh[4]; uint2 u; } cv;
#pragma unroll
            for (int r = 0; r < 4; r++) cv.hh[r] = (__bf16)((acc[i][j][r] + bv) * scl);
            *(uint2*)&sm[col_local * 136 + row_base] = cv.u;
          }
      }
      __syncthreads();
      {
        int dh = tid >> 2, tq = tid & 3;
        const u16* src = &sm[dh * 136 + tq * 32];
        u16* dp = dstV + ((size_t)((bb * 16 + h0 + p) * 128) + off + dh) * 2048 + t0 + tq * 32;
#pragma unroll
        for (int k = 0; k < 4; k++)
          *(uint4*)(dp + k * 8) = *(const uint4*)(src + k * 8);
      }
      __syncthreads();
    }
    return;
  }

#pragma unroll
  for (int i = 0; i < 4; i++)
#pragma unroll
    for (int j = 0; j < 4; j++)
#pragma unroll
      for (int r = 0; r < 4; r++) {
        int grow = brow + wrow + i * 16 + hi * 4 + r;
        int gcol = bcol + wcol + j * 16 + ql;
        float v = (acc[i][j][r] + bias[gcol]) * scl;
        if (MODE == 0) {
          ((float*)args.dst[z])[(size_t)grow * 1024 + gcol] = v;
        } else {
          int bb = grow >> 11, tt = grow & 2047;
          int h = gcol >> 6, dh = gcol & 63;
          ((u16*)args.dst[z])[(((size_t)(bb * 16 + h) * 2048 + tt) << 7) + off + dh] = f2bf(v);
        }
      }
}

// ---------------- flash attention: dual q-sets, disjoint 32-k windows, 128-k tiles ----
// Block: 256 thr = 4 waves, q-tile 64 rows. Wave w: ALL 64 q (2 fragment sets) x k-window
// [w*32, +32) of each staged 128-k tile. Each staged byte ds_read exactly once.
// 4-way k-split merged via LDS at epilogue. Fixed-max softmax (exact, validated).
__global__ __launch_bounds__(256, 2) void attn_kernel(
    const u16* __restrict__ Q, const u16* __restrict__ K, const u16* __restrict__ Vt,
    u16* __restrict__ Or, u16* __restrict__ Oi) {
  const int bh = blockIdx.x;
  const int ii = (int)gridDim.y - 1 - (int)blockIdx.y;  // 31..0, big work first
  const int tid = threadIdx.x, w = tid >> 6, lane = tid & 63;
  const int q32 = lane & 31;
  const int hb = lane >> 5;                 // lane half
  const int b = bh >> 4, hh = bh & 15;

  __shared__ u16 lKV[2][128 * 128];         // [0]=K tile 128k x 128c, [1]=V 128dv x 128t
  __shared__ u16 lP[8][1024];               // [w*2+set][32q x 32k], granule-swizzled
  u16* lK = lKV[0];
  u16* lV = lKV[1];

  const int qA = ii * 64 + q32;             // set A q row
  const int qB = qA + 32;                   // set B q row
  const int kwin = w * 32;                  // this wave's k-window within each 128-k tile

  bf16x8 qfA[8], qfB[8];
#pragma unroll
  for (int kk = 0; kk < 8; kk++) {
    qfA[kk] = *(const bf16x8*)(Q + ((size_t)bh * 2048 + qA) * 128 + kk * 16 + hb * 8);
    qfB[kk] = *(const bf16x8*)(Q + ((size_t)bh * 2048 + qB) * 128 + kk * 16 + hb * 8);
  }

  f32x16 oA[4] = {}, oB[4] = {};            // O^T: dv = jv2*32 + (reg&3)+8*(reg>>2)+4*hb
  float lA = 0.f, lB = 0.f;

  const int nt2 = (ii + 2) >> 1;            // 128-k tiles

  auto stageKV = [&](int jt) {
#pragma unroll
    for (int s = 0; s < 8; s++) {
      int op = w * 8 + s;
      int srow = op * 4 + (lane >> 4);
      int csrc = (lane & 15) ^ (srow & 15);
      gl2lds16(K + ((size_t)bh * 2048 + jt * 128 + srow) * 128 + csrc * 8, &lK[op * 512]);
    }
#pragma unroll
    for (int s = 0; s < 8; s++) {
      int op = w * 8 + s;
      int dv = op * 4 + (lane >> 4);
      int csrc = (lane & 15) ^ (dv & 15);
      gl2lds16(Vt + ((size_t)bh * 128 + dv) * 2048 + jt * 128 + csrc * 8, &lV[op * 512]);
    }
  };

  for (int jt = 0; jt < nt2; jt++) {
    stageKV(jt);
    asm volatile("s_waitcnt vmcnt(0)" ::: "memory");
    __syncthreads();

    // wave-uniform skip: window entirely above block's max q?
    if (jt * 128 + kwin <= ii * 64 + 63) {
      // ---- S^T = K Q^T : one kf read feeds both q-sets ----
      f32x16 sA = {}, sB = {};
      __builtin_amdgcn_s_setprio(1);
#pragma unroll
      for (int kk = 0; kk < 8; kk++) {
        int ch = kk * 2 + hb;
        int r = kwin + q32;
        bf16x8 kf = *(const bf16x8*)&lK[r * 128 + ((ch ^ (r & 15)) * 8)];
        sA = __builtin_amdgcn_mfma_f32_32x32x16_bf16(kf, qfA[kk], sA, 0, 0, 0);
        sB = __builtin_amdgcn_mfma_f32_32x32x16_bf16(kf, qfB[kk], sB, 0, 0, 0);
      }
      __builtin_amdgcn_s_setprio(0);

      // ---- causal mask (wave-uniform trigger) ----
      if (jt * 128 + kwin + 31 > ii * 64) {
#pragma unroll
        for (int reg = 0; reg < 16; reg++) {
          int krow = (reg & 3) + 8 * (reg >> 2) + 4 * hb;
          int kg = jt * 128 + kwin + krow;
          if (kg > qA) sA[reg] = -1e30f;
          if (kg > qB) sB[reg] = -1e30f;
        }
      }

      // ---- fixed-max softmax P = e^(s-16); strips for both sets ----
#pragma unroll
      for (int rq = 0; rq < 4; rq++) {
        float a0 = exp2f(__builtin_fmaf(sA[rq * 4 + 0], L2E, NEG16L2E));
        float a1 = exp2f(__builtin_fmaf(sA[rq * 4 + 1], L2E, NEG16L2E));
        float a2 = exp2f(__builtin_fmaf(sA[rq * 4 + 2], L2E, NEG16L2E));
        float a3 = exp2f(__builtin_fmaf(sA[rq * 4 + 3], L2E, NEG16L2E));
        lA += (a0 + a1) + (a2 + a3);
        int byte_off = q32 * 64 + ((rq ^ (q32 & 3)) * 16) + hb * 8;
        uint2 pk2;
        pk2.x = cvtpk(a0, a1);
        pk2.y = cvtpk(a2, a3);
        *(uint2*)((char*)&lP[w * 2][0] + byte_off) = pk2;

        float b0 = exp2f(__builtin_fmaf(sB[rq * 4 + 0], L2E, NEG16L2E));
        float b1 = exp2f(__builtin_fmaf(sB[rq * 4 + 1], L2E, NEG16L2E));
        float b2 = exp2f(__builtin_fmaf(sB[rq * 4 + 2], L2E, NEG16L2E));
        float b3 = exp2f(__builtin_fmaf(sB[rq * 4 + 3], L2E, NEG16L2E));
        lB += (b0 + b1) + (b2 + b3);
        pk2.x = cvtpk(b0, b1);
        pk2.y = cvtpk(b2, b3);
        *(uint2*)((char*)&lP[w * 2 + 1][0] + byte_off) = pk2;
      }
      asm volatile("s_waitcnt lgkmcnt(0)" ::: "memory");
      __builtin_amdgcn_sched_barrier(0);

      // ---- O^T += V^T P^T : one vf read feeds both q-sets ----
      __builtin_amdgcn_s_setprio(1);
#pragma unroll
      for (int kk2 = 0; kk2 < 2; kk2++) {
        int G = kk2 * 2 + hb;
        int pb = q32 * 64 + ((G ^ (q32 & 3)) * 16);
        bf16x8 pfA = *(const bf16x8*)((char*)&lP[w * 2][0] + pb);
        bf16x8 pfB = *(const bf16x8*)((char*)&lP[w * 2 + 1][0] + pb);
#pragma unroll
        for (int jv2 = 0; jv2 < 4; jv2++) {
          int dv = jv2 * 32 + q32;
          int g = w * 4 + kk2 * 2 + hb;
          bf16x8 vf = *(const bf16x8*)&lV[dv * 128 + ((g ^ (dv & 15)) * 8)];
          oA[jv2] = __builtin_amdgcn_mfma_f32_32x32x16_bf16(vf, pfA, oA[jv2], 0, 0, 0);
          oB[jv2] = __builtin_amdgcn_mfma_f32_32x32x16_bf16(vf, pfB, oB[jv2], 0, 0, 0);
        }
      }
      __builtin_amdgcn_s_setprio(0);
    }

    __syncthreads();   // all reads done before next stage overwrites
  }

  // ---- 4-way k-split merge through LDS (2 dv-rounds of 64) ----
  lA += __shfl_xor(lA, 32);
  lB += __shfl_xor(lB, 32);
  float* mL = (float*)&lP[0][0];            // 4 waves x 64 q = 1KB
  float* mrg = (float*)&lKV[0][0];          // 4 regions x 16KB

  if (lane < 32) {
    mL[w * 64 + q32] = lA;
    mL[w * 64 + 32 + q32] = lB;
  }

  float linv = 0.f;
#pragma unroll
  for (int r = 0; r < 2; r++) {
    // write phase: this wave's partials for dv in [r*64, r*64+64)
#pragma unroll
    for (int set = 0; set < 2; set++) {
      int qcol = set * 32 + q32;
#pragma unroll
      for (int jl = 0; jl < 2; jl++) {
        int jv2 = r * 2 + jl;
#pragma unroll
        for (int rq = 0; rq < 4; rq++) {
          int dvb = jl * 32 + rq * 8 + 4 * hb;
          int dvs = (dvb + 4 * qcol) & 63;
          f32x4 t;
          if (set == 0) {
            t[0] = oA[jv2][rq * 4 + 0]; t[1] = oA[jv2][rq * 4 + 1];
            t[2] = oA[jv2][rq * 4 + 2]; t[3] = oA[jv2][rq * 4 + 3];
          } else {
            t[0] = oB[jv2][rq * 4 + 0]; t[1] = oB[jv2][rq * 4 + 1];
            t[2] = oB[jv2][rq * 4 + 2]; t[3] = oB[jv2][rq * 4 + 3];
          }
          *(f32x4*)&mrg[w * 4096 + qcol * 64 + dvs] = t;
        }
      }
    }
    __syncthreads();

    // read+merge+store: wave w owns q-rows [w*16, w*16+16)
    int qr = w * 16 + (lane >> 2);
    if (r == 0) {
      float lt = mL[qr] + mL[64 + qr] + mL[128 + qr] + mL[192 + qr];
      linv = 1.f / lt;
    }
    u16* dst = (r == 0) ? Or : Oi;
    const size_t obase = ((size_t)b * 2048 + ii * 64 + qr) * 1024 + hh * 64 + (lane & 3) * 16;
#pragma unroll
    for (int c = 0; c < 4; c++) {
      int dv4 = (lane & 3) * 16 + c * 4;
      int dvs = (dv4 + 4 * qr) & 63;
      f32x4 s0 = *(const f32x4*)&mrg[0 * 4096 + qr * 64 + dvs];
      f32x4 s1 = *(const f32x4*)&mrg[1 * 4096 + qr * 64 + dvs];
      f32x4 s2 = *(const f32x4*)&mrg[2 * 4096 + qr * 64 + dvs];
      f32x4 s3 = *(const f32x4*)&mrg[3 * 4096 + qr * 64 + dvs];
      f32x4 sum = (s0 + s1) + (s2 + s3);
      union { __bf16 hh4[4]; ushort4 u; } cv;
#pragma unroll
      for (int j = 0; j < 4; j++) cv.hh4[j] = (__bf16)(sum[j] * linv);
      *(ushort4*)(dst + obase + c * 4) = cv.u;
    }
    if (r == 0) __syncthreads();   // round-0 reads done before round-1 overwrites
  }
}

// ---------------- host launch ----------------
extern "C" void kernel_launch(void* const* d_in, const int* in_sizes, int n_in,
                              void* d_out, int out_size, void* d_ws, size_t ws_size,
                              hipStream_t stream) {
  (void)in_sizes; (void)n_in; (void)out_size; (void)ws_size;

  const float* x_real = (const float*)d_in[0];
  const float* x_imag = (const float*)d_in[1];

  char* ws = (char*)d_ws;
  size_t off = 0;
  auto alloc = [&](size_t bytes) {
    void* p = ws + off;
    off += (bytes + 255) & ~(size_t)255;
    return p;
  };
  const size_t MK = 4096ull * 1024;
  u16* xr16 = (u16*)alloc(MK * 2);
  u16* xi16 = (u16*)alloc(MK * 2);
  u16* Wt   = (u16*)alloc(8ull * 1024 * 1024 * 2);
  u16* Qc   = (u16*)alloc(32ull * 2048 * 128 * 2);
  u16* Kc   = (u16*)alloc(32ull * 2048 * 128 * 2);
  u16* Vt   = (u16*)alloc(32ull * 2048 * 128 * 2);
  u16* Or   = (u16*)alloc(MK * 2);
  u16* Oi   = (u16*)alloc(MK * 2);

  cvt_bf16_2<<<dim3(1024, 2), 256, 0, stream>>>(x_real, x_imag, xr16, xi16, (int)MK);

  WPtrs wp;
  wp.w[0] = (const float*)d_in[2];
  wp.w[1] = (const float*)d_in[4];
  wp.w[2] = (const float*)d_in[6];
  wp.w[3] = (const float*)d_in[8];
  wp.w[4] = (const float*)d_in[10];
  wp.w[5] = (const float*)d_in[12];
  wp.w[6] = (const float*)d_in[14];
  wp.w[7] = (const float*)d_in[16];
  cvt_w_t<<<dim3(32, 32, 8), 256, 0, stream>>>(wp, Wt);

  GemmArgs pa{};
  const u16* xs[2] = {xr16, xi16};
  for (int z = 0; z < 6; z++) {
    pa.A[z] = xs[z & 1];
    pa.Wt[z] = Wt + (size_t)z * 1048576;
    pa.off[z] = (z & 1) * 64;
    pa.vt[z] = (z >= 4) ? 1 : 0;
    pa.scale[z] = (z < 2) ? 0.125f : 1.0f;  // score scale folded into Q
  }
  pa.bias[0] = (const float*)d_in[3];
  pa.bias[1] = (const float*)d_in[5];
  pa.bias[2] = (const float*)d_in[7];
  pa.bias[3] = (const float*)d_in[9];
  pa.bias[4] = (const float*)d_in[11];
  pa.bias[5] = (const float*)d_in[13];
  pa.dst[0] = Qc; pa.dst[1] = Qc;
  pa.dst[2] = Kc; pa.dst[3] = Kc;
  pa.dst[4] = Vt; pa.dst[5] = Vt;
  gemm_bf16<1><<<dim3(32, 8, 6), 256, 16384, stream>>>(pa);

  attn_kernel<<<dim3(32, 32), 256, 0, stream>>>(Qc, Kc, Vt, Or, Oi);

  GemmArgs fa{};
  fa.A[0] = Or; fa.A[1] = Oi;
  fa.Wt[0] = Wt + 6ull * 1048576;
  fa.Wt[1] = Wt + 7ull * 1048576;
  fa.bias[0] = (const float*)d_in[15];
  fa.bias[1] = (const float*)d_in[17];
  fa.dst[0] = (float*)d_out;
  fa.dst[1] = (float*)d_out + MK;
  fa.off[0] = 0; fa.off[1] = 0;
  fa.vt[0] = 0; fa.vt[1] = 0;
  fa.scale[0] = 1.0f; fa.scale[1] = 1.0f;
  gemm_bf16<0><<<dim3(32, 8, 2), 256, 16384, stream>>>(fa);
}

// Round 16
// 175.144 us; speedup vs baseline: 1.3772x; 1.3772x over previous
//
#include <hip/hip_runtime.h>
#include <hip/hip_bf16.h>

// ComplexAttention: x(2,2048,1024) fp32, 8x W(1024,1024)+b(1024).
// Pipeline: cvt -> 6 proj GEMMs (V written pre-transposed) -> flash attn -> 2 final GEMMs.
// R1-R8: ladder to 175.6us. R9/R10 FAILED. R11: 32x32 attn, 175.0us (BEST).
// R12 dbuf FLAT; R13 occupancy FLAT; R14 register-reuse FAILED (accumulators eat 128 of
//     256 unified regs -> qf spilled to scratch, FETCH 25->158MB, attn 133us).
// R15: revert to R11 exactly. Component ceilings (measured, multi-attempt): gemm<1> ~73us
//     (128^2 3/CU structure at K=1024), attn ~62us (LDS-pipe bound, 5 structures), cvt ~16us
//     (BW floor), gemm<0> ~23us. Sum ~= 175 achieved.

typedef __attribute__((ext_vector_type(8))) __bf16 bf16x8;
typedef __attribute__((ext_vector_type(4))) float f32x4;
typedef __attribute__((ext_vector_type(16))) float f32x16;
typedef unsigned short u16;
typedef unsigned int u32;

#define L2E 1.44269504088896340736f
#define NEG16L2E (-23.0831207542234f)   // -16 * log2(e)

__device__ __forceinline__ void gl2lds16(const void* g, void* l) {
  __builtin_amdgcn_global_load_lds(
      (const __attribute__((address_space(1))) unsigned int*)g,
      (__attribute__((address_space(3))) unsigned int*)l, 16, 0, 0);
}

__device__ __forceinline__ u16 f2bf(float f) {
  union { float f; unsigned u; } v;
  v.f = f;
  unsigned r = v.u + 0x7FFFu + ((v.u >> 16) & 1u);
  return (u16)(r >> 16);
}

__device__ __forceinline__ u32 cvtpk(float lo, float hi) {
  u32 d;
  asm("v_cvt_pk_bf16_f32 %0, %1, %2" : "=v"(d) : "v"(lo), "v"(hi));
  return d;
}

// ---------------- fp32 -> bf16 convert (both tensors, one launch) ----------------
__global__ void cvt_bf16_2(const float* __restrict__ a, const float* __restrict__ bsrc,
                           u16* __restrict__ oa, u16* __restrict__ ob, int n) {
  const float* in = blockIdx.y ? bsrc : a;
  u16* out = blockIdx.y ? ob : oa;
  int stride = gridDim.x * blockDim.x * 4;
  for (int i = (blockIdx.x * blockDim.x + threadIdx.x) * 4; i < n; i += stride) {
    float4 v = *(const float4*)(in + i);
    ushort4 o;
    o.x = f2bf(v.x); o.y = f2bf(v.y); o.z = f2bf(v.z); o.w = f2bf(v.w);
    *(ushort4*)(out + i) = o;
  }
}

// ---------------- W (K x N) fp32 -> Wt (N x K) bf16 ----------------
struct WPtrs { const float* w[8]; };

__global__ void cvt_w_t(WPtrs ptrs, u16* __restrict__ out) {
  __shared__ float tile[32][33];
  const float* W = ptrs.w[blockIdx.z];
  u16* o = out + ((size_t)blockIdx.z << 20);
  int tx = threadIdx.x & 31, ty = threadIdx.x >> 5;
  int bx = blockIdx.x * 32, by = blockIdx.y * 32;
#pragma unroll
  for (int k = 0; k < 4; k++) {
    int r = by + ty + k * 8;
    tile[ty + k * 8][tx] = W[(size_t)r * 1024 + bx + tx];
  }
  __syncthreads();
#pragma unroll
  for (int k = 0; k < 4; k++) {
    int n = bx + ty + k * 8;
    o[(size_t)n * 1024 + by + tx] = f2bf(tile[tx][ty + k * 8]);
  }
}

// ---------------- batched 128x128 GEMM, A(M x 1024) * Wt(N x 1024)^T + bias ----------------
struct GemmArgs {
  const u16* A[6];
  const u16* Wt[6];
  const float* bias[6];
  void* dst[6];
  int off[6];
  int vt[6];
  float scale[6];
};

template <int MODE>
__global__ __launch_bounds__(256, 2) void gemm_bf16(GemmArgs args) {
  extern __shared__ u16 dynpad[];   // 16KB pad at launch -> 48KB/block -> 3 blocks/CU
  const int z = blockIdx.z;
  const u16* __restrict__ A = args.A[z];
  const u16* __restrict__ Bt = args.Wt[z];
  const float* __restrict__ bias = args.bias[z];
  const int brow = blockIdx.x * 128;
  const int bcol = blockIdx.y * 128;

  __shared__ u16 smem[2][2][128 * 32];

  const int tid = threadIdx.x;
  const int w = tid >> 6, lane = tid & 63;
  const int ql = lane & 15, hi = lane >> 4;
  const int wrow = (w >> 1) * 64, wcol = (w & 1) * 64;

  if (args.off[z] == -12345) ((volatile u16*)dynpad)[0] = 0;  // keep dyn-LDS alive, never true

  f32x4 acc[4][4] = {};

  auto stage = [&](int buf, int t) {
    int k0 = t * 32;
#pragma unroll
    for (int s = 0; s < 2; s++) {
      int q = w * 2 + s;
      int lr = q * 16 + (lane >> 2);
      int csrc = (lane & 3) ^ ((lr >> 1) & 3);
      gl2lds16(A + (size_t)(brow + lr) * 1024 + k0 + csrc * 8, &smem[0][buf][q * 512]);
    }
#pragma unroll
    for (int s = 0; s < 2; s++) {
      int q = w * 2 + s;
      int lr = q * 16 + (lane >> 2);
      int csrc = (lane & 3) ^ ((lr >> 1) & 3);
      gl2lds16(Bt + (size_t)(bcol + lr) * 1024 + k0 + csrc * 8, &smem[1][buf][q * 512]);
    }
  };

  stage(0, 0);
  __syncthreads();

  int buf = 0;
  for (int t = 0; t < 32; t++) {
    if (t + 1 < 32) stage(buf ^ 1, t + 1);
    bf16x8 a[4], b[4];
#pragma unroll
    for (int i = 0; i < 4; i++) {
      int row = wrow + i * 16 + ql;
      int cs = hi ^ ((row >> 1) & 3);
      a[i] = *(const bf16x8*)&smem[0][buf][row * 32 + cs * 8];
      int col = wcol + i * 16 + ql;
      int cs2 = hi ^ ((col >> 1) & 3);
      b[i] = *(const bf16x8*)&smem[1][buf][col * 32 + cs2 * 8];
    }
#pragma unroll
    for (int i = 0; i < 4; i++)
#pragma unroll
      for (int j = 0; j < 4; j++)
        acc[i][j] = __builtin_amdgcn_mfma_f32_16x16x32_bf16(a[i], b[j], acc[i][j], 0, 0, 0);
    __syncthreads();
    buf ^= 1;
  }

  const int off = args.off[z];
  const float scl = args.scale[z];

  if (MODE == 1 && args.vt[z]) {
    // ---- V path: transpose C-tile in LDS, write Vt[(bh,dv,t)] coalesced ----
    u16* sm = &smem[0][0][0];
    const int bb = brow >> 11, t0 = brow & 2047;
    const int h0 = bcol >> 6;
    u16* dstV = (u16*)args.dst[z];
#pragma unroll
    for (int p = 0; p < 2; p++) {
      if ((w & 1) == p) {
#pragma unroll
        for (int i = 0; i < 4; i++)
#pragma unroll
          for (int j = 0; j < 4; j++) {
            int col_local = j * 16 + ql;
            int row_base = wrow + i * 16 + hi * 4;
            float bv = bias[bcol + p * 64 + col_local];
            union { __bf16 hh[4]; uint2 u; } cv;
#pragma unroll
            for (int r = 0; r < 4; r++) cv.hh[r] = (__bf16)((acc[i][j][r] + bv) * scl);
            *(uint2*)&sm[col_local * 136 + row_base] = cv.u;
          }
      }
      __syncthreads();
      {
        int dh = tid >> 2, tq = tid & 3;
        const u16* src = &sm[dh * 136 + tq * 32];
        u16* dp = dstV + ((size_t)((bb * 16 + h0 + p) * 128) + off + dh) * 2048 + t0 + tq * 32;
#pragma unroll
        for (int k = 0; k < 4; k++)
          *(uint4*)(dp + k * 8) = *(const uint4*)(src + k * 8);
      }
      __syncthreads();
    }
    return;
  }

#pragma unroll
  for (int i = 0; i < 4; i++)
#pragma unroll
    for (int j = 0; j < 4; j++)
#pragma unroll
      for (int r = 0; r < 4; r++) {
        int grow = brow + wrow + i * 16 + hi * 4 + r;
        int gcol = bcol + wcol + j * 16 + ql;
        float v = (acc[i][j][r] + bias[gcol]) * scl;
        if (MODE == 0) {
          ((float*)args.dst[z])[(size_t)grow * 1024 + gcol] = v;
        } else {
          int bb = grow >> 11, tt = grow & 2047;
          int h = gcol >> 6, dh = gcol & 63;
          ((u16*)args.dst[z])[(((size_t)(bb * 16 + h) * 2048 + tt) << 7) + off + dh] = f2bf(v);
        }
      }
}

// ---------------- flash attention: 32x32 MFMA, shared 128-k tile, k-split wave pairs ----
// Block: 256 thr = 4 waves. Wave w: q-rows [ii*64 + (w&1)*32, +32), k-half (w>>1) of each
// staged 128-k tile. P via per-wave swizzled LDS strip. Fixed-max softmax (exact).
__global__ __launch_bounds__(256, 2) void attn_kernel(
    const u16* __restrict__ Q, const u16* __restrict__ K, const u16* __restrict__ Vt,
    u16* __restrict__ Or, u16* __restrict__ Oi) {
  const int bh = blockIdx.x;
  const int ii = (int)gridDim.y - 1 - (int)blockIdx.y;  // 31..0, big work first
  const int tid = threadIdx.x, w = tid >> 6, lane = tid & 63;
  const int q32 = lane & 31;
  const int hb = lane >> 5;                 // lane half
  const int wq = w & 1, wk = w >> 1;
  const int b = bh >> 4, hh = bh & 15;

  __shared__ u16 lK[128 * 128];             // [k-row][c], 32KB, XOR-swizzled 16B chunks
  __shared__ u16 lV[128 * 128];             // [dv][t],    32KB, XOR-swizzled
  __shared__ u16 lP[4][32 * 64];            // per-wave [q32][key 64], 16B-granule swizzled

  const int q = ii * 64 + wq * 32 + q32;    // this lane's q row

  // Q fragments (B-operand, 32x32x16): col=q, k-elems kk*16 + hb*8 + [0,8)
  bf16x8 qf[8];
#pragma unroll
  for (int kk = 0; kk < 8; kk++)
    qf[kk] = *(const bf16x8*)(Q + ((size_t)bh * 2048 + q) * 128 + kk * 16 + hb * 8);

  f32x16 o[4] = {};                         // O^T: dv = jv2*32 + (reg&3)+8*(reg>>2)+4*hb
  float l = 0.f;

  const int nIter = (ii + 2) >> 1;          // ceil((ii+1)/2) 128-k tiles

  for (int jt = 0; jt < nIter; jt++) {
    // ---- stage shared 128-k tile (all 4 waves, 16 ops each) ----
#pragma unroll
    for (int s8 = 0; s8 < 8; s8++) {
      int op = w * 8 + s8;
      int srow = op * 4 + (lane >> 4);
      int csrc = (lane & 15) ^ (srow & 15);
      gl2lds16(K + ((size_t)bh * 2048 + jt * 128 + srow) * 128 + csrc * 8, &lK[op * 512]);
    }
#pragma unroll
    for (int s8 = 0; s8 < 8; s8++) {
      int op = w * 8 + s8;
      int dv = op * 4 + (lane >> 4);
      int csrc = (lane & 15) ^ (dv & 15);
      gl2lds16(Vt + ((size_t)bh * 128 + dv) * 2048 + jt * 128 + csrc * 8, &lV[op * 512]);
    }
    asm volatile("s_waitcnt vmcnt(0)" ::: "memory");
    __syncthreads();

    // wave-uniform skip: window [jt*128+wk*64, +64) entirely above this wave's max q?
    if (jt * 128 + wk * 64 <= ii * 64 + wq * 32 + 31) {
      // ---- S^T = K Q^T over this wave's 64-k window ----
      f32x16 s0 = {}, s1 = {};
      __builtin_amdgcn_s_setprio(1);
#pragma unroll
      for (int kk = 0; kk < 8; kk++) {
        int ch = kk * 2 + hb;
        int r0 = wk * 64 + q32;
        int r1 = r0 + 32;
        bf16x8 kf0 = *(const bf16x8*)&lK[r0 * 128 + (ch ^ (r0 & 15)) * 8];
        bf16x8 kf1 = *(const bf16x8*)&lK[r1 * 128 + (ch ^ (r1 & 15)) * 8];
        s0 = __builtin_amdgcn_mfma_f32_32x32x16_bf16(kf0, qf[kk], s0, 0, 0, 0);
        s1 = __builtin_amdgcn_mfma_f32_32x32x16_bf16(kf1, qf[kk], s1, 0, 0, 0);
      }
      __builtin_amdgcn_s_setprio(0);

      // ---- causal mask (wave-uniform trigger) ----
      if (jt * 128 + wk * 64 + 63 > ii * 64 + wq * 32) {
#pragma unroll
        for (int reg = 0; reg < 16; reg++) {
          int krow = (reg & 3) + 8 * (reg >> 2) + 4 * hb;
          int k0g = jt * 128 + wk * 64 + krow;
          if (k0g > q) s0[reg] = -1e30f;
          if (k0g + 32 > q) s1[reg] = -1e30f;
        }
      }

      // ---- fixed-max softmax P = e^(s-16); write P strip (8B per (j2,rq)) ----
#pragma unroll
      for (int j2 = 0; j2 < 2; j2++)
#pragma unroll
        for (int rq = 0; rq < 4; rq++) {
          float p0, p1, p2, p3;
          if (j2 == 0) {
            p0 = exp2f(__builtin_fmaf(s0[rq * 4 + 0], L2E, NEG16L2E));
            p1 = exp2f(__builtin_fmaf(s0[rq * 4 + 1], L2E, NEG16L2E));
            p2 = exp2f(__builtin_fmaf(s0[rq * 4 + 2], L2E, NEG16L2E));
            p3 = exp2f(__builtin_fmaf(s0[rq * 4 + 3], L2E, NEG16L2E));
          } else {
            p0 = exp2f(__builtin_fmaf(s1[rq * 4 + 0], L2E, NEG16L2E));
            p1 = exp2f(__builtin_fmaf(s1[rq * 4 + 1], L2E, NEG16L2E));
            p2 = exp2f(__builtin_fmaf(s1[rq * 4 + 2], L2E, NEG16L2E));
            p3 = exp2f(__builtin_fmaf(s1[rq * 4 + 3], L2E, NEG16L2E));
          }
          l += (p0 + p1) + (p2 + p3);
          // keys kb = j2*32 + 8rq + 4hb .. +3 ; granule g = j2*4+rq, half = hb
          int g = j2 * 4 + rq;
          int byte_off = q32 * 128 + ((g ^ (q32 & 7)) * 16) + hb * 8;
          uint2 pk2;
          pk2.x = cvtpk(p0, p1);
          pk2.y = cvtpk(p2, p3);
          *(uint2*)((char*)&lP[w][0] + byte_off) = pk2;
        }
      // within-wave write->read through LDS
      asm volatile("s_waitcnt lgkmcnt(0)" ::: "memory");
      __builtin_amdgcn_sched_barrier(0);

      // ---- O^T += V^T P^T ----
      __builtin_amdgcn_s_setprio(1);
#pragma unroll
      for (int kk2 = 0; kk2 < 4; kk2++) {
        int G = kk2 * 2 + hb;
        bf16x8 pf = *(const bf16x8*)((char*)&lP[w][0] + q32 * 128 + ((G ^ (q32 & 7)) * 16));
#pragma unroll
        for (int jv2 = 0; jv2 < 4; jv2++) {
          int dv = jv2 * 32 + q32;
          int ch = wk * 8 + kk2 * 2 + hb;
          bf16x8 vf = *(const bf16x8*)&lV[dv * 128 + (ch ^ (dv & 15)) * 8];
          o[jv2] = __builtin_amdgcn_mfma_f32_32x32x16_bf16(vf, pf, o[jv2], 0, 0, 0);
        }
      }
      __builtin_amdgcn_s_setprio(0);
    }

    __syncthreads();   // all reads done before next stage overwrites
  }

  // ---- k-split merge: waves 2,3 deposit O,l partials; waves 0,1 add + store ----
  l += __shfl_xor(l, 32);                   // full row-sum for this wave's k-half
  float* mO = (float*)&lK[0];               // 2 x 16KB regions
  float* mL = (float*)&lV[0];

  if (w >= 2) {
#pragma unroll
    for (int jv2 = 0; jv2 < 4; jv2++)
#pragma unroll
      for (int rq = 0; rq < 4; rq++) {
        int dvb = jv2 * 32 + rq * 8 + 4 * hb;
        int dvs = (dvb + 4 * q32) & 127;
        f32x4 t;
        t[0] = o[jv2][rq * 4 + 0]; t[1] = o[jv2][rq * 4 + 1];
        t[2] = o[jv2][rq * 4 + 2]; t[3] = o[jv2][rq * 4 + 3];
        *(f32x4*)&mO[(w - 2) * 4096 + q32 * 128 + dvs] = t;
      }
    if (lane < 32) mL[(w - 2) * 32 + q32] = l;
  }
  __syncthreads();

  if (w < 2) {
    float lt = l + mL[w * 32 + q32];
    float linv = 1.f / lt;
    const size_t obase = ((size_t)b * 2048 + q) * 1024 + hh * 64;
#pragma unroll
    for (int jv2 = 0; jv2 < 4; jv2++)
#pragma unroll
      for (int rq = 0; rq < 4; rq++) {
        int dvb = jv2 * 32 + rq * 8 + 4 * hb;
        int dvs = (dvb + 4 * q32) & 127;
        f32x4 part = *(const f32x4*)&mO[w * 4096 + q32 * 128 + dvs];
        union { __bf16 hh4[4]; ushort4 u; } cv;
#pragma unroll
        for (int r = 0; r < 4; r++)
          cv.hh4[r] = (__bf16)((o[jv2][rq * 4 + r] + part[r]) * linv);
        u16* dst = (jv2 < 2) ? Or : Oi;
        *(ushort4*)(dst + obase + (jv2 & 1) * 32 + rq * 8 + 4 * hb) = cv.u;
      }
  }
}

// ---------------- host launch ----------------
extern "C" void kernel_launch(void* const* d_in, const int* in_sizes, int n_in,
                              void* d_out, int out_size, void* d_ws, size_t ws_size,
                              hipStream_t stream) {
  (void)in_sizes; (void)n_in; (void)out_size; (void)ws_size;

  const float* x_real = (const float*)d_in[0];
  const float* x_imag = (const float*)d_in[1];

  char* ws = (char*)d_ws;
  size_t off = 0;
  auto alloc = [&](size_t bytes) {
    void* p = ws + off;
    off += (bytes + 255) & ~(size_t)255;
    return p;
  };
  const size_t MK = 4096ull * 1024;
  u16* xr16 = (u16*)alloc(MK * 2);
  u16* xi16 = (u16*)alloc(MK * 2);
  u16* Wt   = (u16*)alloc(8ull * 1024 * 1024 * 2);
  u16* Qc   = (u16*)alloc(32ull * 2048 * 128 * 2);
  u16* Kc   = (u16*)alloc(32ull * 2048 * 128 * 2);
  u16* Vt   = (u16*)alloc(32ull * 2048 * 128 * 2);
  u16* Or   = (u16*)alloc(MK * 2);
  u16* Oi   = (u16*)alloc(MK * 2);

  cvt_bf16_2<<<dim3(1024, 2), 256, 0, stream>>>(x_real, x_imag, xr16, xi16, (int)MK);

  WPtrs wp;
  wp.w[0] = (const float*)d_in[2];
  wp.w[1] = (const float*)d_in[4];
  wp.w[2] = (const float*)d_in[6];
  wp.w[3] = (const float*)d_in[8];
  wp.w[4] = (const float*)d_in[10];
  wp.w[5] = (const float*)d_in[12];
  wp.w[6] = (const float*)d_in[14];
  wp.w[7] = (const float*)d_in[16];
  cvt_w_t<<<dim3(32, 32, 8), 256, 0, stream>>>(wp, Wt);

  GemmArgs pa{};
  const u16* xs[2] = {xr16, xi16};
  for (int z = 0; z < 6; z++) {
    pa.A[z] = xs[z & 1];
    pa.Wt[z] = Wt + (size_t)z * 1048576;
    pa.off[z] = (z & 1) * 64;
    pa.vt[z] = (z >= 4) ? 1 : 0;
    pa.scale[z] = (z < 2) ? 0.125f : 1.0f;  // score scale folded into Q
  }
  pa.bias[0] = (const float*)d_in[3];
  pa.bias[1] = (const float*)d_in[5];
  pa.bias[2] = (const float*)d_in[7];
  pa.bias[3] = (const float*)d_in[9];
  pa.bias[4] = (const float*)d_in[11];
  pa.bias[5] = (const float*)d_in[13];
  pa.dst[0] = Qc; pa.dst[1] = Qc;
  pa.dst[2] = Kc; pa.dst[3] = Kc;
  pa.dst[4] = Vt; pa.dst[5] = Vt;
  gemm_bf16<1><<<dim3(32, 8, 6), 256, 16384, stream>>>(pa);

  attn_kernel<<<dim3(32, 32), 256, 0, stream>>>(Qc, Kc, Vt, Or, Oi);

  GemmArgs fa{};
  fa.A[0] = Or; fa.A[1] = Oi;
  fa.Wt[0] = Wt + 6ull * 1048576;
  fa.Wt[1] = Wt + 7ull * 1048576;
  fa.bias[0] = (const float*)d_in[15];
  fa.bias[1] = (const float*)d_in[17];
  fa.dst[0] = (float*)d_out;
  fa.dst[1] = (float*)d_out + MK;
  fa.off[0] = 0; fa.off[1] = 0;
  fa.vt[0] = 0; fa.vt[1] = 0;
  fa.scale[0] = 1.0f; fa.scale[1] = 1.0f;
  gemm_bf16<0><<<dim3(32, 8, 2), 256, 16384, stream>>>(fa);
}